// Round 1
// baseline (37.949 us; speedup 1.0000x reference)
//
#include <hip/hip_runtime.h>
#include <stdint.h>

// BERT input representation: out = x@W_emb + seg + b_emb*(1+Sw) + b_seg + PE
// B=64 S=512 F=64 D=1024 SEG=8 -> GEMM M=32768 K=64 N=1024, fused epilogue.

typedef __attribute__((ext_vector_type(8))) short short8;
typedef __attribute__((ext_vector_type(4))) float f32x4;

#define D_DIM 1024
#define BM 64
#define BN 128

__device__ __forceinline__ unsigned short f2bf(float f) {
  unsigned u = __float_as_uint(f);
  u = (u + 0x7FFFu + ((u >> 16) & 1u)) >> 16;  // RNE f32 -> bf16
  return (unsigned short)u;
}

__global__ __launch_bounds__(256) void bert_input_kernel(
    const float* __restrict__ x, const float* __restrict__ W,
    const float* __restrict__ b_emb, const float* __restrict__ w_seg,
    const float* __restrict__ b_seg, float* __restrict__ out) {
  // LDS: W tile in MFMA-B fragment layout [nf(8)][kf(2)][lane(64)][j(8)] bf16
  __shared__ unsigned short ldsb[8 * 2 * 64 * 8];

  const int tid = threadIdx.x;
  const int lane = tid & 63;
  const int wave = tid >> 6;
  const int bid = blockIdx.x;
  const int nblk = bid & 7;   // 1024/128 = 8 col-blocks
  const int mblk = bid >> 3;  // 32768/64 = 512 row-blocks
  const int nbase = nblk * BN;
  const int mbase = mblk * BM;

  // ---- stage W tile (64 x 128 f32) -> LDS bf16, fragment-order ----
  {
    const int k = tid >> 2;        // 0..63
    const int cq = (tid & 3) * 4;  // float4 col offset
    const int kf = k >> 5;
    const int j = k & 7;
    const int laneb = ((k >> 3) & 3) << 4;
    const float4* wrow =
        reinterpret_cast<const float4*>(W + (size_t)k * D_DIM + nbase);
#pragma unroll
    for (int q = 0; q < 8; ++q) {
      int c = cq + q * 16;  // tile-local col, 0..127
      float4 v = wrow[c >> 2];
      int nf = c >> 4;
      int base = ((nf * 2 + kf) * 64 + (laneb | (c & 15))) * 8 + j;
      ldsb[base + 0 * 8] = f2bf(v.x);
      ldsb[base + 1 * 8] = f2bf(v.y);
      ldsb[base + 2 * 8] = f2bf(v.z);
      ldsb[base + 3 * 8] = f2bf(v.w);
    }
  }

  // ---- per-thread segment weights ----
  float Sw = 0.f;
#pragma unroll
  for (int i = 0; i < 8; ++i) Sw += w_seg[i];
  const int g = lane >> 4;
  float wl[4];
#pragma unroll
  for (int j = 0; j < 4; ++j) wl[j] = w_seg[(g & 1) * 4 + j];
  const float bseg = b_seg[0];

  // ---- A fragments direct from global (x rows are K=64 contiguous f32) ----
  const int mw = wave >> 1;  // 0..1
  const int nw = wave & 1;   // 0..1
  short8 afrag[2][2];
  {
    const int row0 = mbase + mw * 32 + (lane & 15);
    const int k0 = (lane >> 4) * 8;
#pragma unroll
    for (int mf = 0; mf < 2; ++mf) {
#pragma unroll
      for (int kf = 0; kf < 2; ++kf) {
        const float* p = x + (size_t)(row0 + mf * 16) * 64 + kf * 32 + k0;
        float4 v0 = *reinterpret_cast<const float4*>(p);
        float4 v1 = *reinterpret_cast<const float4*>(p + 4);
        short8 a;
        a[0] = (short)f2bf(v0.x); a[1] = (short)f2bf(v0.y);
        a[2] = (short)f2bf(v0.z); a[3] = (short)f2bf(v0.w);
        a[4] = (short)f2bf(v1.x); a[5] = (short)f2bf(v1.y);
        a[6] = (short)f2bf(v1.z); a[7] = (short)f2bf(v1.w);
        afrag[mf][kf] = a;
      }
    }
  }

  __syncthreads();

  // ---- B fragments from LDS (one ds_read_b128 each) ----
  short8 bfrag[4][2];
#pragma unroll
  for (int nf = 0; nf < 4; ++nf) {
#pragma unroll
    for (int kf = 0; kf < 2; ++kf) {
      int nfg = nw * 4 + nf;
      bfrag[nf][kf] = *reinterpret_cast<const short8*>(
          &ldsb[((nfg * 2 + kf) * 64 + lane) * 8]);
    }
  }

  // ---- MFMA: K=64 in two K=32 steps ----
  f32x4 acc[2][4];
#pragma unroll
  for (int mf = 0; mf < 2; ++mf) {
#pragma unroll
    for (int nf = 0; nf < 4; ++nf) {
      f32x4 c = {0.f, 0.f, 0.f, 0.f};
      c = __builtin_amdgcn_mfma_f32_16x16x32_bf16(afrag[mf][0], bfrag[nf][0],
                                                  c, 0, 0, 0);
      c = __builtin_amdgcn_mfma_f32_16x16x32_bf16(afrag[mf][1], bfrag[nf][1],
                                                  c, 0, 0, 0);
      acc[mf][nf] = c;
    }
  }

  // ---- fused epilogue: seg reduce + biases + sinusoidal PE + store ----
  const float inv2pi = 0.15915494309189535f;
  const float KLOG = 0.02595256324130752f;  // log2(10000)/512

#pragma unroll
  for (int nf = 0; nf < 4; ++nf) {
    const int col = nbase + (nw * 4 + nf) * 16 + (lane & 15);
    const float cconst = b_emb[col] * (1.f + Sw) + bseg;
    // div (angular rate) in revolutions; cos = sin shifted by 0.25 rev
    const float divrev = exp2f(-(float)(col >> 1) * KLOG) * inv2pi;
    const float qshift = (col & 1) ? 0.25f : 0.f;
#pragma unroll
    for (int mf = 0; mf < 2; ++mf) {
      f32x4 a = acc[mf][nf];
      // segment reduction: rows (g*4+j); segment = 8 rows spanning g, g^1
      float p = wl[0] * a[0] + wl[1] * a[1] + wl[2] * a[2] + wl[3] * a[3];
      p += __shfl_xor(p, 16);
      const int rbase = mbase + mw * 32 + mf * 16 + g * 4;
      const int sbase = rbase & 511;  // position within sequence
#pragma unroll
      for (int j = 0; j < 4; ++j) {
        float rev = (float)(sbase + j) * divrev + qshift;
        rev = rev - floorf(rev);
        float pe = __builtin_amdgcn_sinf(rev);
        out[(size_t)(rbase + j) * D_DIM + col] = a[j] + p + cconst + pe;
      }
    }
  }
}

extern "C" void kernel_launch(void* const* d_in, const int* in_sizes, int n_in,
                              void* d_out, int out_size, void* d_ws,
                              size_t ws_size, hipStream_t stream) {
  const float* x = (const float*)d_in[0];
  const float* W = (const float*)d_in[1];
  const float* b_emb = (const float*)d_in[2];
  const float* w_seg = (const float*)d_in[3];
  const float* b_seg = (const float*)d_in[4];
  float* out = (float*)d_out;

  dim3 grid(4096);  // (32768/64) * (1024/128)
  dim3 block(256);
  bert_input_kernel<<<grid, block, 0, stream>>>(x, W, b_emb, w_seg, b_seg,
                                                out);
}